// Round 6
// baseline (244.314 us; speedup 1.0000x reference)
//
#include <hip/hip_runtime.h>
#include <hip/hip_fp16.h>
#include <math.h>

#define N_NODES 50000
#define N_EDGES 800000
#define IN_FEATS 128
#define N_HIDDEN 64
#define OUT_FEATS 40
#define DIM 8
#define GT_TILES ((N_NODES + 63) / 64)            // 782 gemm tiles
#define FILL_BLOCKS (N_EDGES / 256)               // 3125 fill blocks, 1 edge/thread
#define SCAN_NB ((N_NODES + 255) / 256)           // 196 scan blocks

typedef _Float16 half8 __attribute__((ext_vector_type(8)));
typedef float floatx4 __attribute__((ext_vector_type(4)));

// ---------------- wave-wide inclusive scan (64 lanes) ----------------
__device__ __forceinline__ int wave_incl_scan(int x, int lane) {
#pragma unroll
    for (int off = 1; off < 64; off <<= 1) {
        int v = __shfl_up(x, off, 64);
        if (lane >= off) x += v;
    }
    return x;
}

// ============================================================================
// K1: in-degree histogram + per-edge rank (returning atomic).
// ============================================================================
__global__ __launch_bounds__(256) void hist_kernel(const int* __restrict__ dst,
                                                   int* __restrict__ counts,
                                                   unsigned short* __restrict__ rank) {
    int i = blockIdx.x * 256 + threadIdx.x;      // quad index
    if (i * 4 >= N_EDGES) return;
    int4 d = ((const int4*)dst)[i];
    ushort4 r;
    r.x = (unsigned short)atomicAdd(&counts[d.x], 1);
    r.y = (unsigned short)atomicAdd(&counts[d.y], 1);
    r.z = (unsigned short)atomicAdd(&counts[d.z], 1);
    r.w = (unsigned short)atomicAdd(&counts[d.w], 1);
    ((ushort4*)rank)[i] = r;                      // coalesced 8B store
}

// ============================================================================
// K2a/b/c: hierarchical scan (every phase wide; single-block scan = 50us floor).
// ============================================================================
__global__ __launch_bounds__(256) void scan_partial_kernel(const int* __restrict__ counts,
                                                           int* __restrict__ offsets,
                                                           int* __restrict__ partials) {
    const int tid = threadIdx.x, bid = blockIdx.x;
    const int i = bid * 256 + tid;
    const int lane = tid & 63, wid = tid >> 6;
    int x = (i < N_NODES) ? counts[i] : 0;
    int incl = wave_incl_scan(x, lane);
    __shared__ int wsum[4];
    if (lane == 63) wsum[wid] = incl;
    __syncthreads();
    int base = 0;
#pragma unroll
    for (int w = 0; w < 4; ++w)
        if (w < wid) base += wsum[w];
    if (i < N_NODES) offsets[i] = base + incl - x;   // block-local exclusive
    if (tid == 255) partials[bid] = base + incl;     // block total
}

__global__ __launch_bounds__(256) void scan_base_kernel(int* __restrict__ partials) {
    const int tid = threadIdx.x;
    const int lane = tid & 63, wid = tid >> 6;
    int x = (tid < SCAN_NB) ? partials[tid] : 0;
    int incl = wave_incl_scan(x, lane);
    __shared__ int wsum[4];
    if (lane == 63) wsum[wid] = incl;
    __syncthreads();
    int base = 0;
#pragma unroll
    for (int w = 0; w < 4; ++w)
        if (w < wid) base += wsum[w];
    if (tid < SCAN_NB) partials[tid] = base + incl - x;  // exclusive base per block
}

__global__ __launch_bounds__(256) void scan_add_kernel(int* __restrict__ offsets,
                                                       const int* __restrict__ partials) {
    const int i = blockIdx.x * 256 + threadIdx.x;
    if (i < N_NODES) offsets[i] += partials[blockIdx.x];
    if (i == N_NODES) offsets[N_NODES] = N_EDGES;    // block 195 covers i==50000
}

// ============================================================================
// K3: gemm1 MFMA tiles first, then ATOMIC-FREE CSR fill (pos = offsets+rank).
// ============================================================================
__global__ __launch_bounds__(256) void fillgemm_kernel(
    const float* __restrict__ features, const float* __restrict__ W1,
    const int* __restrict__ src, const int* __restrict__ dst,
    const float* __restrict__ ew,
    const float* __restrict__ mu1, const float* __restrict__ is1,
    const float* __restrict__ mu2, const float* __restrict__ is2,
    const int* __restrict__ offsets, const unsigned short* __restrict__ rank,
    int2* __restrict__ csr, __half* __restrict__ h1)
{
    const int tid = threadIdx.x;
    __shared__ __align__(16) __half WT[64][136];   // W1^T fp16, 17.4 KB

    if (blockIdx.x >= GT_TILES) {
        // ---- fill: one edge per thread (3125*256 == 800000 exactly) ----
        int e = (blockIdx.x - GT_TILES) * 256 + tid;
        int sN = src[e];
        int dN = dst[e];
        unsigned short rk = rank[e];
        const float4* ew4 = (const float4*)(ew + (size_t)e * DIM);
        float4 wa = ew4[0], wb = ew4[1];
        float v[8] = {wa.x, wa.y, wa.z, wa.w, wb.x, wb.y, wb.z, wb.w};
        float s1 = 0.f, s2 = 0.f;
#pragma unroll
        for (int d = 0; d < DIM; ++d) {
            float d1 = v[d] - mu1[d]; float a1 = is1[d];
            float d2 = v[d] - mu2[d]; float a2 = is2[d];
            s1 += d1 * d1 * a1 * a1;
            s2 += d2 * d2 * a2 * a2;
        }
        __half2 g = __floats2half2_rn(expf(-0.5f * s1), expf(-0.5f * s2));
        int2 rec;
        rec.x = sN;
        rec.y = *reinterpret_cast<int*>(&g);
        int pos = offsets[dN] + rk;                 // offsets: 200KB, L2-hot
        __builtin_nontemporal_store(*reinterpret_cast<long long*>(&rec),
                                    reinterpret_cast<long long*>(&csr[pos]));
        return;
    }

    // ---- gemm1 tile: 64 nodes x 64 feats, MFMA 16x16x32 f16, A from global ----
    int nodeBase = blockIdx.x * 64;
    for (int rep = 0; rep < 32; ++rep) {
        int idx = tid + rep * 256;          // 0..8191 = k*64 + n
        int k = idx >> 6, n = idx & 63;
        WT[n][k] = __float2half(W1[idx]);
    }
    __syncthreads();

    int lane = tid & 63, w = tid >> 6;
    int m = lane & 15, quad = lane >> 4;
    int row = nodeBase + w * 16 + m;
    int rowc = (row < N_NODES) ? row : (N_NODES - 1);
    const float* fr = features + (size_t)rowc * IN_FEATS;

    floatx4 acc0 = {0.f,0.f,0.f,0.f}, acc1 = acc0, acc2 = acc0, acc3 = acc0;
#pragma unroll
    for (int kc = 0; kc < 4; ++kc) {
        float4 fa = *(const float4*)(fr + kc * 32 + quad * 8);
        float4 fb = *(const float4*)(fr + kc * 32 + quad * 8 + 4);
        union { half8 v; __half2 h2[4]; } A;
        A.h2[0] = __floats2half2_rn(fa.x, fa.y);
        A.h2[1] = __floats2half2_rn(fa.z, fa.w);
        A.h2[2] = __floats2half2_rn(fb.x, fb.y);
        A.h2[3] = __floats2half2_rn(fb.z, fb.w);
        half8 b0 = *(const half8*)&WT[ 0 + m][kc * 32 + quad * 8];
        half8 b1 = *(const half8*)&WT[16 + m][kc * 32 + quad * 8];
        half8 b2 = *(const half8*)&WT[32 + m][kc * 32 + quad * 8];
        half8 b3 = *(const half8*)&WT[48 + m][kc * 32 + quad * 8];
        acc0 = __builtin_amdgcn_mfma_f32_16x16x32_f16(A.v, b0, acc0, 0, 0, 0);
        acc1 = __builtin_amdgcn_mfma_f32_16x16x32_f16(A.v, b1, acc1, 0, 0, 0);
        acc2 = __builtin_amdgcn_mfma_f32_16x16x32_f16(A.v, b2, acc2, 0, 0, 0);
        acc3 = __builtin_amdgcn_mfma_f32_16x16x32_f16(A.v, b3, acc3, 0, 0, 0);
    }
    int nodeRow = nodeBase + w * 16 + quad * 4;
#pragma unroll
    for (int r = 0; r < 4; ++r) {
        int n = nodeRow + r;
        if (n < N_NODES) {
            size_t base = (size_t)n * N_HIDDEN + m;
            h1[base +  0] = __float2half(acc0[r]);
            h1[base + 16] = __float2half(acc1[r]);
            h1[base + 32] = __float2half(acc2[r]);
            h1[base + 48] = __float2half(acc3[r]);
        }
    }
}

// ============================================================================
// agg1 + gemm2: ONE NODE PER WAVE, 4 lane-groups of 16, uint2 row loads.
// One VMEM instr fetches 4 edge rows; 2x unroll -> 8 edges in flight/wave.
// Cross-group reduce = 2 shfl_xor. gemm2 reads W2 from LDS, xs as float4.
// ============================================================================
__global__ __launch_bounds__(256) void agg1_gemm2_kernel(const __half* __restrict__ h,
                                                         const int* __restrict__ offsets,
                                                         const int2* __restrict__ csr,
                                                         const float* __restrict__ b,
                                                         const float* __restrict__ W2,
                                                         __half* __restrict__ h2) {
    __shared__ float xs[4][64];
    __shared__ float W2s[N_HIDDEN * OUT_FEATS];     // 10 KB
    const uint2* h64 = (const uint2*)h;             // h1 row = 16 uint2
    const int tid = threadIdx.x;
    const int w = tid >> 6, lane = tid & 63;
    const int g = lane >> 4, p = lane & 15;         // group g: edge slot; p: 8B chunk
    const int n = blockIdx.x * 4 + w;

    // stage W2 while aggregation runs (consumed after the sync)
    for (int i = tid; i < N_HIDDEN * OUT_FEATS; i += 256)
        W2s[i] = W2[i];

    int beg = offsets[n], end = offsets[n + 1];

    float ax0 = 0.f, ax1 = 0.f, ax2 = 0.f, ax3 = 0.f;
    for (int j = beg; j < end; j += 8) {
        int ja = j + g, jb = j + g + 4;
        // loop entered only when beg<end, so end-1 >= beg is a valid index
        int2 ra = csr[(ja < end) ? ja : (end - 1)];
        int2 rb = csr[(jb < end) ? jb : (end - 1)];
        float ga = (ja < end) ? __low2float(*reinterpret_cast<__half2*>(&ra.y)) : 0.f;
        float gb = (jb < end) ? __low2float(*reinterpret_cast<__half2*>(&rb.y)) : 0.f;
        uint2 va = h64[(size_t)ra.x * 16 + p];
        uint2 vb = h64[(size_t)rb.x * 16 + p];
        float2 a0 = __half22float2(*reinterpret_cast<__half2*>(&va.x));
        float2 a1 = __half22float2(*reinterpret_cast<__half2*>(&va.y));
        float2 b0 = __half22float2(*reinterpret_cast<__half2*>(&vb.x));
        float2 b1 = __half22float2(*reinterpret_cast<__half2*>(&vb.y));
        ax0 += a0.x * ga; ax1 += a0.y * ga;
        ax2 += a1.x * ga; ax3 += a1.y * ga;
        ax0 += b0.x * gb; ax1 += b0.y * gb;
        ax2 += b1.x * gb; ax3 += b1.y * gb;
    }
    // reduce across the 4 groups (lane bits 4,5)
    ax0 += __shfl_xor(ax0, 16, 64); ax1 += __shfl_xor(ax1, 16, 64);
    ax2 += __shfl_xor(ax2, 16, 64); ax3 += __shfl_xor(ax3, 16, 64);
    ax0 += __shfl_xor(ax0, 32, 64); ax1 += __shfl_xor(ax1, 32, 64);
    ax2 += __shfl_xor(ax2, 32, 64); ax3 += __shfl_xor(ax3, 32, 64);

    if (g == 0) {
        float4 bb = *(const float4*)&b[4 * p];
        *(float4*)&xs[w][4 * p] =
            make_float4(ax0 + bb.x, ax1 + bb.y, ax2 + bb.z, ax3 + bb.w);
    }
    __syncthreads();

    // gemm2: 4 nodes x 40 outs = 160 outputs
    if (tid < 4 * OUT_FEATS) {
        int node = tid / OUT_FEATS, t = tid % OUT_FEATS;
        const float* xr = xs[node];
        float acc = 0.f;
#pragma unroll
        for (int k = 0; k < N_HIDDEN; k += 4) {
            float4 x4 = *(const float4*)&xr[k];
            acc += x4.x * W2s[(k + 0) * OUT_FEATS + t];
            acc += x4.y * W2s[(k + 1) * OUT_FEATS + t];
            acc += x4.z * W2s[(k + 2) * OUT_FEATS + t];
            acc += x4.w * W2s[(k + 3) * OUT_FEATS + t];
        }
        h2[(size_t)(blockIdx.x * 4 + node) * OUT_FEATS + t] = __float2half(acc);
    }
}

// ---------------- agg layer 2 + b2 + log_softmax: 2 nodes per wave ----------------
__global__ __launch_bounds__(256) void agg2_kernel(const __half* __restrict__ h,
                                                   const int* __restrict__ offsets,
                                                   const int2* __restrict__ csr,
                                                   const float* __restrict__ b,
                                                   float* __restrict__ out) {
    const unsigned* h32 = (const unsigned*)h;   // h2 row = 20 dwords
    const int tid = threadIdx.x;
    const int w = tid >> 6, lane = tid & 63;
    const int hf = lane >> 5, p = lane & 31;
    const int n = blockIdx.x * 8 + w * 2 + hf;
    const int pc = (p < 20) ? p : 19;           // clamp: no divergence, no OOB
    int beg = offsets[n], end = offsets[n + 1];

    float ax = 0.f, ay = 0.f;
    int j = beg;
    for (; j + 4 <= end; j += 4) {
        int2 r0 = csr[j + 0], r1 = csr[j + 1], r2 = csr[j + 2], r3 = csr[j + 3];
        unsigned v0 = h32[(size_t)r0.x * 20 + pc];
        unsigned v1 = h32[(size_t)r1.x * 20 + pc];
        unsigned v2 = h32[(size_t)r2.x * 20 + pc];
        unsigned v3 = h32[(size_t)r3.x * 20 + pc];
        float g0 = __high2float(*reinterpret_cast<__half2*>(&r0.y));
        float g1 = __high2float(*reinterpret_cast<__half2*>(&r1.y));
        float g2 = __high2float(*reinterpret_cast<__half2*>(&r2.y));
        float g3 = __high2float(*reinterpret_cast<__half2*>(&r3.y));
        float2 f0 = __half22float2(*reinterpret_cast<__half2*>(&v0));
        float2 f1 = __half22float2(*reinterpret_cast<__half2*>(&v1));
        float2 f2 = __half22float2(*reinterpret_cast<__half2*>(&v2));
        float2 f3 = __half22float2(*reinterpret_cast<__half2*>(&v3));
        ax += f0.x * g0; ay += f0.y * g0;
        ax += f1.x * g1; ay += f1.y * g1;
        ax += f2.x * g2; ay += f2.y * g2;
        ax += f3.x * g3; ay += f3.y * g3;
    }
    for (; j < end; ++j) {
        int2 r = csr[j];
        unsigned v = h32[(size_t)r.x * 20 + pc];
        float g = __high2float(*reinterpret_cast<__half2*>(&r.y));
        float2 f = __half22float2(*reinterpret_cast<__half2*>(&v));
        ax += f.x * g; ay += f.y * g;
    }

    bool valid = (p < 20);
    float vx = valid ? ax + b[2 * p]     : -INFINITY;
    float vy = valid ? ay + b[2 * p + 1] : -INFINITY;
    float m = fmaxf(vx, vy);
#pragma unroll
    for (int off = 16; off; off >>= 1)
        m = fmaxf(m, __shfl_xor(m, off, 32));   // reduce within each 32-lane half
    float ex = valid ? (expf(vx - m) + expf(vy - m)) : 0.f;
#pragma unroll
    for (int off = 16; off; off >>= 1)
        ex += __shfl_xor(ex, off, 32);
    float ls = logf(ex);
    if (valid) {
        float2 o = make_float2(vx - m - ls, vy - m - ls);
        *(float2*)&out[(size_t)n * OUT_FEATS + 2 * p] = o;
    }
}

extern "C" void kernel_launch(void* const* d_in, const int* in_sizes, int n_in,
                              void* d_out, int out_size, void* d_ws, size_t ws_size,
                              hipStream_t stream) {
    const float* features    = (const float*)d_in[0];
    const float* edge_weight = (const float*)d_in[1];
    const int*   src         = (const int*)d_in[2];
    const int*   dst         = (const int*)d_in[3];
    const float* W1          = (const float*)d_in[4];
    const float* b1          = (const float*)d_in[5];
    const float* mu1         = (const float*)d_in[6];
    const float* is1         = (const float*)d_in[7];
    const float* W2          = (const float*)d_in[8];
    const float* b2          = (const float*)d_in[9];
    const float* mu2         = (const float*)d_in[10];
    const float* is2         = (const float*)d_in[11];
    float* out = (float*)d_out;

    // Workspace: csr int2[800k] 6.4M | h1 half[3.2M] 6.4M | h2 half[2M] 4M
    //            | counts[50k] 200K | rank u16[800k] 1.6M | offsets[50k+1] 200K
    //            | partials[256] 1K                                  (~18.8 MB)
    int2*           csr     = (int2*)d_ws;
    __half*         h1      = (__half*)(csr + N_EDGES);
    __half*         h2      = h1 + (size_t)N_NODES * N_HIDDEN;
    int*            counts  = (int*)(h2 + (size_t)N_NODES * OUT_FEATS);
    unsigned short* rank    = (unsigned short*)(counts + N_NODES);
    int*            offsets = (int*)(rank + N_EDGES);
    int*            partials= offsets + N_NODES + 1;

    hipMemsetAsync(counts, 0, N_NODES * sizeof(int), stream);

    hist_kernel<<<(N_EDGES / 4 + 255) / 256, 256, 0, stream>>>(dst, counts, rank);

    scan_partial_kernel<<<SCAN_NB, 256, 0, stream>>>(counts, offsets, partials);
    scan_base_kernel<<<1, 256, 0, stream>>>(partials);
    scan_add_kernel<<<SCAN_NB, 256, 0, stream>>>(offsets, partials);

    fillgemm_kernel<<<GT_TILES + FILL_BLOCKS, 256, 0, stream>>>(
        features, W1, src, dst, edge_weight, mu1, is1, mu2, is2, offsets, rank, csr, h1);

    agg1_gemm2_kernel<<<N_NODES / 4, 256, 0, stream>>>(h1, offsets, csr, b1, W2, h2);

    agg2_kernel<<<N_NODES / 8, 256, 0, stream>>>(h2, offsets, csr, b2, out);
}

// Round 7
// 238.741 us; speedup vs baseline: 1.0233x; 1.0233x over previous
//
#include <hip/hip_runtime.h>
#include <hip/hip_fp16.h>
#include <math.h>

#define N_NODES 50000
#define N_EDGES 800000
#define IN_FEATS 128
#define N_HIDDEN 64
#define OUT_FEATS 40
#define DIM 8
#define GT_TILES ((N_NODES + 63) / 64)            // 782 gemm tiles
#define FILL_BLOCKS (N_EDGES / 256)               // 3125 fill blocks, 1 edge/thread
#define SCAN_NB ((N_NODES + 255) / 256)           // 196 scan blocks

typedef _Float16 half8 __attribute__((ext_vector_type(8)));
typedef float floatx4 __attribute__((ext_vector_type(4)));

// ---------------- wave-wide inclusive scan (64 lanes) ----------------
__device__ __forceinline__ int wave_incl_scan(int x, int lane) {
#pragma unroll
    for (int off = 1; off < 64; off <<= 1) {
        int v = __shfl_up(x, off, 64);
        if (lane >= off) x += v;
    }
    return x;
}

// ============================================================================
// K1: in-degree histogram + per-edge rank (returning atomic).
// ============================================================================
__global__ __launch_bounds__(256) void hist_kernel(const int* __restrict__ dst,
                                                   int* __restrict__ counts,
                                                   unsigned short* __restrict__ rank) {
    int i = blockIdx.x * 256 + threadIdx.x;      // quad index
    if (i * 4 >= N_EDGES) return;
    int4 d = ((const int4*)dst)[i];
    ushort4 r;
    r.x = (unsigned short)atomicAdd(&counts[d.x], 1);
    r.y = (unsigned short)atomicAdd(&counts[d.y], 1);
    r.z = (unsigned short)atomicAdd(&counts[d.z], 1);
    r.w = (unsigned short)atomicAdd(&counts[d.w], 1);
    ((ushort4*)rank)[i] = r;                      // coalesced 8B store
}

// ============================================================================
// K2a/b/c: hierarchical scan (every phase wide; single-block scan = 50us floor).
// ============================================================================
__global__ __launch_bounds__(256) void scan_partial_kernel(const int* __restrict__ counts,
                                                           int* __restrict__ offsets,
                                                           int* __restrict__ partials) {
    const int tid = threadIdx.x, bid = blockIdx.x;
    const int i = bid * 256 + tid;
    const int lane = tid & 63, wid = tid >> 6;
    int x = (i < N_NODES) ? counts[i] : 0;
    int incl = wave_incl_scan(x, lane);
    __shared__ int wsum[4];
    if (lane == 63) wsum[wid] = incl;
    __syncthreads();
    int base = 0;
#pragma unroll
    for (int w = 0; w < 4; ++w)
        if (w < wid) base += wsum[w];
    if (i < N_NODES) offsets[i] = base + incl - x;   // block-local exclusive
    if (tid == 255) partials[bid] = base + incl;     // block total
}

__global__ __launch_bounds__(256) void scan_base_kernel(int* __restrict__ partials) {
    const int tid = threadIdx.x;
    const int lane = tid & 63, wid = tid >> 6;
    int x = (tid < SCAN_NB) ? partials[tid] : 0;
    int incl = wave_incl_scan(x, lane);
    __shared__ int wsum[4];
    if (lane == 63) wsum[wid] = incl;
    __syncthreads();
    int base = 0;
#pragma unroll
    for (int w = 0; w < 4; ++w)
        if (w < wid) base += wsum[w];
    if (tid < SCAN_NB) partials[tid] = base + incl - x;  // exclusive base per block
}

__global__ __launch_bounds__(256) void scan_add_kernel(int* __restrict__ offsets,
                                                       const int* __restrict__ partials) {
    const int i = blockIdx.x * 256 + threadIdx.x;
    if (i < N_NODES) offsets[i] += partials[blockIdx.x];
    if (i == N_NODES) offsets[N_NODES] = N_EDGES;    // block 195 covers i==50000
}

// ============================================================================
// K3: gemm1 MFMA tiles first, then ATOMIC-FREE CSR fill (pos = offsets+rank).
// ============================================================================
__global__ __launch_bounds__(256) void fillgemm_kernel(
    const float* __restrict__ features, const float* __restrict__ W1,
    const int* __restrict__ src, const int* __restrict__ dst,
    const float* __restrict__ ew,
    const float* __restrict__ mu1, const float* __restrict__ is1,
    const float* __restrict__ mu2, const float* __restrict__ is2,
    const int* __restrict__ offsets, const unsigned short* __restrict__ rank,
    int2* __restrict__ csr, __half* __restrict__ h1)
{
    const int tid = threadIdx.x;
    __shared__ __align__(16) __half WT[64][136];   // W1^T fp16, 17.4 KB

    if (blockIdx.x >= GT_TILES) {
        // ---- fill: one edge per thread (3125*256 == 800000 exactly) ----
        int e = (blockIdx.x - GT_TILES) * 256 + tid;
        int sN = src[e];
        int dN = dst[e];
        unsigned short rk = rank[e];
        const float4* ew4 = (const float4*)(ew + (size_t)e * DIM);
        float4 wa = ew4[0], wb = ew4[1];
        float v[8] = {wa.x, wa.y, wa.z, wa.w, wb.x, wb.y, wb.z, wb.w};
        float s1 = 0.f, s2 = 0.f;
#pragma unroll
        for (int d = 0; d < DIM; ++d) {
            float d1 = v[d] - mu1[d]; float a1 = is1[d];
            float d2 = v[d] - mu2[d]; float a2 = is2[d];
            s1 += d1 * d1 * a1 * a1;
            s2 += d2 * d2 * a2 * a2;
        }
        __half2 g = __floats2half2_rn(expf(-0.5f * s1), expf(-0.5f * s2));
        int2 rec;
        rec.x = sN;
        rec.y = *reinterpret_cast<int*>(&g);
        int pos = offsets[dN] + rk;                 // offsets: 200KB, L2-hot
        __builtin_nontemporal_store(*reinterpret_cast<long long*>(&rec),
                                    reinterpret_cast<long long*>(&csr[pos]));
        return;
    }

    // ---- gemm1 tile: 64 nodes x 64 feats, MFMA 16x16x32 f16, A from global ----
    int nodeBase = blockIdx.x * 64;
    for (int rep = 0; rep < 32; ++rep) {
        int idx = tid + rep * 256;          // 0..8191 = k*64 + n
        int k = idx >> 6, n = idx & 63;
        WT[n][k] = __float2half(W1[idx]);
    }
    __syncthreads();

    int lane = tid & 63, w = tid >> 6;
    int m = lane & 15, quad = lane >> 4;
    int row = nodeBase + w * 16 + m;
    int rowc = (row < N_NODES) ? row : (N_NODES - 1);
    const float* fr = features + (size_t)rowc * IN_FEATS;

    floatx4 acc0 = {0.f,0.f,0.f,0.f}, acc1 = acc0, acc2 = acc0, acc3 = acc0;
#pragma unroll
    for (int kc = 0; kc < 4; ++kc) {
        float4 fa = *(const float4*)(fr + kc * 32 + quad * 8);
        float4 fb = *(const float4*)(fr + kc * 32 + quad * 8 + 4);
        union { half8 v; __half2 h2[4]; } A;
        A.h2[0] = __floats2half2_rn(fa.x, fa.y);
        A.h2[1] = __floats2half2_rn(fa.z, fa.w);
        A.h2[2] = __floats2half2_rn(fb.x, fb.y);
        A.h2[3] = __floats2half2_rn(fb.z, fb.w);
        half8 b0 = *(const half8*)&WT[ 0 + m][kc * 32 + quad * 8];
        half8 b1 = *(const half8*)&WT[16 + m][kc * 32 + quad * 8];
        half8 b2 = *(const half8*)&WT[32 + m][kc * 32 + quad * 8];
        half8 b3 = *(const half8*)&WT[48 + m][kc * 32 + quad * 8];
        acc0 = __builtin_amdgcn_mfma_f32_16x16x32_f16(A.v, b0, acc0, 0, 0, 0);
        acc1 = __builtin_amdgcn_mfma_f32_16x16x32_f16(A.v, b1, acc1, 0, 0, 0);
        acc2 = __builtin_amdgcn_mfma_f32_16x16x32_f16(A.v, b2, acc2, 0, 0, 0);
        acc3 = __builtin_amdgcn_mfma_f32_16x16x32_f16(A.v, b3, acc3, 0, 0, 0);
    }
    int nodeRow = nodeBase + w * 16 + quad * 4;
#pragma unroll
    for (int r = 0; r < 4; ++r) {
        int n = nodeRow + r;
        if (n < N_NODES) {
            size_t base = (size_t)n * N_HIDDEN + m;
            h1[base +  0] = __float2half(acc0[r]);
            h1[base + 16] = __float2half(acc1[r]);
            h1[base + 32] = __float2half(acc2[r]);
            h1[base + 48] = __float2half(acc3[r]);
        }
    }
}

// ============================================================================
// agg1 + gemm2 (R4 structure + 8-DEEP UNROLL): 2 nodes per wave, 32 lanes/row,
// dword loads. 8 csr records then 8 independent row-gathers IN FLIGHT per
// half-wave (R6 showed the compiler minimizes regs to 16 and serializes
// unless the unroll forces live ranges). Tail via clamp + zero weight.
// ============================================================================
__global__ __launch_bounds__(256) void agg1_gemm2_kernel(const __half* __restrict__ h,
                                                         const int* __restrict__ offsets,
                                                         const int2* __restrict__ csr,
                                                         const float* __restrict__ b,
                                                         const float* __restrict__ W2,
                                                         __half* __restrict__ h2) {
    __shared__ float xs[8][64];
    const unsigned* h32 = (const unsigned*)h;   // h1 row = 32 dwords
    const int tid = threadIdx.x;
    const int w = tid >> 6, lane = tid & 63;
    const int hf = lane >> 5, p = lane & 31;
    const int ln = w * 2 + hf;                  // local node 0..7
    const int n = blockIdx.x * 8 + ln;
    int beg = offsets[n], end = offsets[n + 1];

    float ax = 0.f, ay = 0.f;
    for (int j = beg; j < end; j += 8) {        // entered only when beg < end
        int j0 = j + 0, j1 = j + 1, j2 = j + 2, j3 = j + 3;
        int j4 = j + 4, j5 = j + 5, j6 = j + 6, j7 = j + 7;
        int e1 = end - 1;
        int2 r0 = csr[(j0 < end) ? j0 : e1];
        int2 r1 = csr[(j1 < end) ? j1 : e1];
        int2 r2 = csr[(j2 < end) ? j2 : e1];
        int2 r3 = csr[(j3 < end) ? j3 : e1];
        int2 r4 = csr[(j4 < end) ? j4 : e1];
        int2 r5 = csr[(j5 < end) ? j5 : e1];
        int2 r6 = csr[(j6 < end) ? j6 : e1];
        int2 r7 = csr[(j7 < end) ? j7 : e1];
        unsigned v0 = h32[(size_t)r0.x * 32 + p];
        unsigned v1 = h32[(size_t)r1.x * 32 + p];
        unsigned v2 = h32[(size_t)r2.x * 32 + p];
        unsigned v3 = h32[(size_t)r3.x * 32 + p];
        unsigned v4 = h32[(size_t)r4.x * 32 + p];
        unsigned v5 = h32[(size_t)r5.x * 32 + p];
        unsigned v6 = h32[(size_t)r6.x * 32 + p];
        unsigned v7 = h32[(size_t)r7.x * 32 + p];
        float g0 = (j0 < end) ? __low2float(*reinterpret_cast<__half2*>(&r0.y)) : 0.f;
        float g1 = (j1 < end) ? __low2float(*reinterpret_cast<__half2*>(&r1.y)) : 0.f;
        float g2 = (j2 < end) ? __low2float(*reinterpret_cast<__half2*>(&r2.y)) : 0.f;
        float g3 = (j3 < end) ? __low2float(*reinterpret_cast<__half2*>(&r3.y)) : 0.f;
        float g4 = (j4 < end) ? __low2float(*reinterpret_cast<__half2*>(&r4.y)) : 0.f;
        float g5 = (j5 < end) ? __low2float(*reinterpret_cast<__half2*>(&r5.y)) : 0.f;
        float g6 = (j6 < end) ? __low2float(*reinterpret_cast<__half2*>(&r6.y)) : 0.f;
        float g7 = (j7 < end) ? __low2float(*reinterpret_cast<__half2*>(&r7.y)) : 0.f;
        float2 f0 = __half22float2(*reinterpret_cast<__half2*>(&v0));
        float2 f1 = __half22float2(*reinterpret_cast<__half2*>(&v1));
        float2 f2 = __half22float2(*reinterpret_cast<__half2*>(&v2));
        float2 f3 = __half22float2(*reinterpret_cast<__half2*>(&v3));
        float2 f4 = __half22float2(*reinterpret_cast<__half2*>(&v4));
        float2 f5 = __half22float2(*reinterpret_cast<__half2*>(&v5));
        float2 f6 = __half22float2(*reinterpret_cast<__half2*>(&v6));
        float2 f7 = __half22float2(*reinterpret_cast<__half2*>(&v7));
        ax += f0.x * g0; ay += f0.y * g0;
        ax += f1.x * g1; ay += f1.y * g1;
        ax += f2.x * g2; ay += f2.y * g2;
        ax += f3.x * g3; ay += f3.y * g3;
        ax += f4.x * g4; ay += f4.y * g4;
        ax += f5.x * g5; ay += f5.y * g5;
        ax += f6.x * g6; ay += f6.y * g6;
        ax += f7.x * g7; ay += f7.y * g7;
    }
    float2 bb = *(const float2*)&b[2 * p];
    *(float2*)&xs[ln][2 * p] = make_float2(ax + bb.x, ay + bb.y);
    __syncthreads();

    // gemm2: 8 nodes x 40 outs = 320 outputs over 256 threads
    for (int o = tid; o < 8 * OUT_FEATS; o += 256) {
        int node = o / OUT_FEATS, t = o % OUT_FEATS;
        const float* xr = xs[node];
        float acc = 0.f;
#pragma unroll
        for (int k = 0; k < N_HIDDEN; ++k)
            acc += xr[k] * W2[k * OUT_FEATS + t];
        h2[(size_t)(blockIdx.x * 8 + node) * OUT_FEATS + t] = __float2half(acc);
    }
}

// ---------------- agg layer 2 + b2 + log_softmax: 8-deep unroll ----------------
__global__ __launch_bounds__(256) void agg2_kernel(const __half* __restrict__ h,
                                                   const int* __restrict__ offsets,
                                                   const int2* __restrict__ csr,
                                                   const float* __restrict__ b,
                                                   float* __restrict__ out) {
    const unsigned* h32 = (const unsigned*)h;   // h2 row = 20 dwords
    const int tid = threadIdx.x;
    const int w = tid >> 6, lane = tid & 63;
    const int hf = lane >> 5, p = lane & 31;
    const int n = blockIdx.x * 8 + w * 2 + hf;
    const int pc = (p < 20) ? p : 19;           // clamp: no divergence, no OOB
    int beg = offsets[n], end = offsets[n + 1];

    float ax = 0.f, ay = 0.f;
    for (int j = beg; j < end; j += 8) {        // entered only when beg < end
        int j0 = j + 0, j1 = j + 1, j2 = j + 2, j3 = j + 3;
        int j4 = j + 4, j5 = j + 5, j6 = j + 6, j7 = j + 7;
        int e1 = end - 1;
        int2 r0 = csr[(j0 < end) ? j0 : e1];
        int2 r1 = csr[(j1 < end) ? j1 : e1];
        int2 r2 = csr[(j2 < end) ? j2 : e1];
        int2 r3 = csr[(j3 < end) ? j3 : e1];
        int2 r4 = csr[(j4 < end) ? j4 : e1];
        int2 r5 = csr[(j5 < end) ? j5 : e1];
        int2 r6 = csr[(j6 < end) ? j6 : e1];
        int2 r7 = csr[(j7 < end) ? j7 : e1];
        unsigned v0 = h32[(size_t)r0.x * 20 + pc];
        unsigned v1 = h32[(size_t)r1.x * 20 + pc];
        unsigned v2 = h32[(size_t)r2.x * 20 + pc];
        unsigned v3 = h32[(size_t)r3.x * 20 + pc];
        unsigned v4 = h32[(size_t)r4.x * 20 + pc];
        unsigned v5 = h32[(size_t)r5.x * 20 + pc];
        unsigned v6 = h32[(size_t)r6.x * 20 + pc];
        unsigned v7 = h32[(size_t)r7.x * 20 + pc];
        float g0 = (j0 < end) ? __high2float(*reinterpret_cast<__half2*>(&r0.y)) : 0.f;
        float g1 = (j1 < end) ? __high2float(*reinterpret_cast<__half2*>(&r1.y)) : 0.f;
        float g2 = (j2 < end) ? __high2float(*reinterpret_cast<__half2*>(&r2.y)) : 0.f;
        float g3 = (j3 < end) ? __high2float(*reinterpret_cast<__half2*>(&r3.y)) : 0.f;
        float g4 = (j4 < end) ? __high2float(*reinterpret_cast<__half2*>(&r4.y)) : 0.f;
        float g5 = (j5 < end) ? __high2float(*reinterpret_cast<__half2*>(&r5.y)) : 0.f;
        float g6 = (j6 < end) ? __high2float(*reinterpret_cast<__half2*>(&r6.y)) : 0.f;
        float g7 = (j7 < end) ? __high2float(*reinterpret_cast<__half2*>(&r7.y)) : 0.f;
        float2 f0 = __half22float2(*reinterpret_cast<__half2*>(&v0));
        float2 f1 = __half22float2(*reinterpret_cast<__half2*>(&v1));
        float2 f2 = __half22float2(*reinterpret_cast<__half2*>(&v2));
        float2 f3 = __half22float2(*reinterpret_cast<__half2*>(&v3));
        float2 f4 = __half22float2(*reinterpret_cast<__half2*>(&v4));
        float2 f5 = __half22float2(*reinterpret_cast<__half2*>(&v5));
        float2 f6 = __half22float2(*reinterpret_cast<__half2*>(&v6));
        float2 f7 = __half22float2(*reinterpret_cast<__half2*>(&v7));
        ax += f0.x * g0; ay += f0.y * g0;
        ax += f1.x * g1; ay += f1.y * g1;
        ax += f2.x * g2; ay += f2.y * g2;
        ax += f3.x * g3; ay += f3.y * g3;
        ax += f4.x * g4; ay += f4.y * g4;
        ax += f5.x * g5; ay += f5.y * g5;
        ax += f6.x * g6; ay += f6.y * g6;
        ax += f7.x * g7; ay += f7.y * g7;
    }

    bool valid = (p < 20);
    float vx = valid ? ax + b[2 * p]     : -INFINITY;
    float vy = valid ? ay + b[2 * p + 1] : -INFINITY;
    float m = fmaxf(vx, vy);
#pragma unroll
    for (int off = 16; off; off >>= 1)
        m = fmaxf(m, __shfl_xor(m, off, 32));   // reduce within each 32-lane half
    float ex = valid ? (expf(vx - m) + expf(vy - m)) : 0.f;
#pragma unroll
    for (int off = 16; off; off >>= 1)
        ex += __shfl_xor(ex, off, 32);
    float ls = logf(ex);
    if (valid) {
        float2 o = make_float2(vx - m - ls, vy - m - ls);
        *(float2*)&out[(size_t)n * OUT_FEATS + 2 * p] = o;
    }
}

extern "C" void kernel_launch(void* const* d_in, const int* in_sizes, int n_in,
                              void* d_out, int out_size, void* d_ws, size_t ws_size,
                              hipStream_t stream) {
    const float* features    = (const float*)d_in[0];
    const float* edge_weight = (const float*)d_in[1];
    const int*   src         = (const int*)d_in[2];
    const int*   dst         = (const int*)d_in[3];
    const float* W1          = (const float*)d_in[4];
    const float* b1          = (const float*)d_in[5];
    const float* mu1         = (const float*)d_in[6];
    const float* is1         = (const float*)d_in[7];
    const float* W2          = (const float*)d_in[8];
    const float* b2          = (const float*)d_in[9];
    const float* mu2         = (const float*)d_in[10];
    const float* is2         = (const float*)d_in[11];
    float* out = (float*)d_out;

    // Workspace: csr int2[800k] 6.4M | h1 half[3.2M] 6.4M | h2 half[2M] 4M
    //            | counts[50k] 200K | rank u16[800k] 1.6M | offsets[50k+1] 200K
    //            | partials[256] 1K                                  (~18.8 MB)
    int2*           csr     = (int2*)d_ws;
    __half*         h1      = (__half*)(csr + N_EDGES);
    __half*         h2      = h1 + (size_t)N_NODES * N_HIDDEN;
    int*            counts  = (int*)(h2 + (size_t)N_NODES * OUT_FEATS);
    unsigned short* rank    = (unsigned short*)(counts + N_NODES);
    int*            offsets = (int*)(rank + N_EDGES);
    int*            partials= offsets + N_NODES + 1;

    hipMemsetAsync(counts, 0, N_NODES * sizeof(int), stream);

    hist_kernel<<<(N_EDGES / 4 + 255) / 256, 256, 0, stream>>>(dst, counts, rank);

    scan_partial_kernel<<<SCAN_NB, 256, 0, stream>>>(counts, offsets, partials);
    scan_base_kernel<<<1, 256, 0, stream>>>(partials);
    scan_add_kernel<<<SCAN_NB, 256, 0, stream>>>(offsets, partials);

    fillgemm_kernel<<<GT_TILES + FILL_BLOCKS, 256, 0, stream>>>(
        features, W1, src, dst, edge_weight, mu1, is1, mu2, is2, offsets, rank, csr, h1);

    agg1_gemm2_kernel<<<N_NODES / 8, 256, 0, stream>>>(h1, offsets, csr, b1, W2, h2);

    agg2_kernel<<<N_NODES / 8, 256, 0, stream>>>(h2, offsets, csr, b2, out);
}

// Round 8
// 237.752 us; speedup vs baseline: 1.0276x; 1.0042x over previous
//
#include <hip/hip_runtime.h>
#include <hip/hip_fp16.h>
#include <math.h>

#define N_NODES 50000
#define N_EDGES 800000
#define IN_FEATS 128
#define N_HIDDEN 64
#define OUT_FEATS 40
#define DIM 8
#define GT_TILES ((N_NODES + 63) / 64)            // 782 gemm tiles
#define HIST_NB ((N_EDGES / 4 + 255) / 256)       // 782 hist blocks
#define FILL_BLOCKS (N_EDGES / 256)               // 3125 fill blocks, 1 edge/thread
#define SCAN_NB ((N_NODES + 255) / 256)           // 196 scan blocks
#define CNT_STRIDE 4                               // counts padded to 16B/counter

typedef _Float16 half8 __attribute__((ext_vector_type(8)));
typedef float floatx4 __attribute__((ext_vector_type(4)));

// ---------------- wave-wide inclusive scan (64 lanes) ----------------
__device__ __forceinline__ int wave_incl_scan(int x, int lane) {
#pragma unroll
    for (int off = 1; off < 64; off <<= 1) {
        int v = __shfl_up(x, off, 64);
        if (lane >= off) x += v;
    }
    return x;
}

// ============================================================================
// K1: MERGED hist + gemm1. Hist blocks FIRST (long pole: 800k returning
// atomics on line-padded counts); gemm1 MFMA tiles after. Both independent of
// scan/fill, so hist's atomic latency hides under gemm compute.
// ============================================================================
__global__ __launch_bounds__(256) void histgemm_kernel(
    const float* __restrict__ features, const float* __restrict__ W1,
    const int* __restrict__ dst,
    int* __restrict__ counts, unsigned short* __restrict__ rank,
    __half* __restrict__ h1)
{
    const int tid = threadIdx.x;
    __shared__ __align__(16) __half WT[64][136];   // W1^T fp16, 17.4 KB

    if (blockIdx.x < HIST_NB) {
        // ---- hist: 4 edges/thread, returning atomics on padded counters ----
        int i = blockIdx.x * 256 + tid;            // quad index
        if (i * 4 >= N_EDGES) return;
        int4 d = ((const int4*)dst)[i];
        ushort4 r;
        r.x = (unsigned short)atomicAdd(&counts[d.x * CNT_STRIDE], 1);
        r.y = (unsigned short)atomicAdd(&counts[d.y * CNT_STRIDE], 1);
        r.z = (unsigned short)atomicAdd(&counts[d.z * CNT_STRIDE], 1);
        r.w = (unsigned short)atomicAdd(&counts[d.w * CNT_STRIDE], 1);
        ((ushort4*)rank)[i] = r;                   // coalesced 8B store
        return;
    }

    // ---- gemm1 tile: 64 nodes x 64 feats, MFMA 16x16x32 f16 ----
    int nodeBase = (blockIdx.x - HIST_NB) * 64;
    for (int rep = 0; rep < 32; ++rep) {
        int idx = tid + rep * 256;          // 0..8191 = k*64 + n
        int k = idx >> 6, n = idx & 63;
        WT[n][k] = __float2half(W1[idx]);
    }
    __syncthreads();

    int lane = tid & 63, w = tid >> 6;
    int m = lane & 15, quad = lane >> 4;
    int row = nodeBase + w * 16 + m;
    int rowc = (row < N_NODES) ? row : (N_NODES - 1);
    const float* fr = features + (size_t)rowc * IN_FEATS;

    floatx4 acc0 = {0.f,0.f,0.f,0.f}, acc1 = acc0, acc2 = acc0, acc3 = acc0;
#pragma unroll
    for (int kc = 0; kc < 4; ++kc) {
        float4 fa = *(const float4*)(fr + kc * 32 + quad * 8);
        float4 fb = *(const float4*)(fr + kc * 32 + quad * 8 + 4);
        union { half8 v; __half2 h2[4]; } A;
        A.h2[0] = __floats2half2_rn(fa.x, fa.y);
        A.h2[1] = __floats2half2_rn(fa.z, fa.w);
        A.h2[2] = __floats2half2_rn(fb.x, fb.y);
        A.h2[3] = __floats2half2_rn(fb.z, fb.w);
        half8 b0 = *(const half8*)&WT[ 0 + m][kc * 32 + quad * 8];
        half8 b1 = *(const half8*)&WT[16 + m][kc * 32 + quad * 8];
        half8 b2 = *(const half8*)&WT[32 + m][kc * 32 + quad * 8];
        half8 b3 = *(const half8*)&WT[48 + m][kc * 32 + quad * 8];
        acc0 = __builtin_amdgcn_mfma_f32_16x16x32_f16(A.v, b0, acc0, 0, 0, 0);
        acc1 = __builtin_amdgcn_mfma_f32_16x16x32_f16(A.v, b1, acc1, 0, 0, 0);
        acc2 = __builtin_amdgcn_mfma_f32_16x16x32_f16(A.v, b2, acc2, 0, 0, 0);
        acc3 = __builtin_amdgcn_mfma_f32_16x16x32_f16(A.v, b3, acc3, 0, 0, 0);
    }
    int nodeRow = nodeBase + w * 16 + quad * 4;
#pragma unroll
    for (int r = 0; r < 4; ++r) {
        int n = nodeRow + r;
        if (n < N_NODES) {
            size_t base = (size_t)n * N_HIDDEN + m;
            h1[base +  0] = __float2half(acc0[r]);
            h1[base + 16] = __float2half(acc1[r]);
            h1[base + 32] = __float2half(acc2[r]);
            h1[base + 48] = __float2half(acc3[r]);
        }
    }
}

// ============================================================================
// K2a/b/c: hierarchical scan over the PADDED counts array.
// ============================================================================
__global__ __launch_bounds__(256) void scan_partial_kernel(const int* __restrict__ counts,
                                                           int* __restrict__ offsets,
                                                           int* __restrict__ partials) {
    const int tid = threadIdx.x, bid = blockIdx.x;
    const int i = bid * 256 + tid;
    const int lane = tid & 63, wid = tid >> 6;
    int x = (i < N_NODES) ? counts[i * CNT_STRIDE] : 0;
    int incl = wave_incl_scan(x, lane);
    __shared__ int wsum[4];
    if (lane == 63) wsum[wid] = incl;
    __syncthreads();
    int base = 0;
#pragma unroll
    for (int w = 0; w < 4; ++w)
        if (w < wid) base += wsum[w];
    if (i < N_NODES) offsets[i] = base + incl - x;   // block-local exclusive
    if (tid == 255) partials[bid] = base + incl;     // block total
}

__global__ __launch_bounds__(256) void scan_base_kernel(int* __restrict__ partials) {
    const int tid = threadIdx.x;
    const int lane = tid & 63, wid = tid >> 6;
    int x = (tid < SCAN_NB) ? partials[tid] : 0;
    int incl = wave_incl_scan(x, lane);
    __shared__ int wsum[4];
    if (lane == 63) wsum[wid] = incl;
    __syncthreads();
    int base = 0;
#pragma unroll
    for (int w = 0; w < 4; ++w)
        if (w < wid) base += wsum[w];
    if (tid < SCAN_NB) partials[tid] = base + incl - x;  // exclusive base per block
}

__global__ __launch_bounds__(256) void scan_add_kernel(int* __restrict__ offsets,
                                                       const int* __restrict__ partials) {
    const int i = blockIdx.x * 256 + threadIdx.x;
    if (i < N_NODES) offsets[i] += partials[blockIdx.x];
    if (i == N_NODES) offsets[N_NODES] = N_EDGES;    // block 195 covers i==50000
}

// ============================================================================
// K3: ATOMIC-FREE CSR fill, standalone (must follow scan).
// pos = offsets[dst] + rank[e]; nontemporal 8B record store.
// ============================================================================
__global__ __launch_bounds__(256) void fill_kernel(
    const int* __restrict__ src, const int* __restrict__ dst,
    const float* __restrict__ ew,
    const float* __restrict__ mu1, const float* __restrict__ is1,
    const float* __restrict__ mu2, const float* __restrict__ is2,
    const int* __restrict__ offsets, const unsigned short* __restrict__ rank,
    int2* __restrict__ csr)
{
    int e = blockIdx.x * 256 + threadIdx.x;        // 3125*256 == 800000 exactly
    int sN = src[e];
    int dN = dst[e];
    unsigned short rk = rank[e];
    const float4* ew4 = (const float4*)(ew + (size_t)e * DIM);
    float4 wa = ew4[0], wb = ew4[1];
    float v[8] = {wa.x, wa.y, wa.z, wa.w, wb.x, wb.y, wb.z, wb.w};
    float s1 = 0.f, s2 = 0.f;
#pragma unroll
    for (int d = 0; d < DIM; ++d) {
        float d1 = v[d] - mu1[d]; float a1 = is1[d];
        float d2 = v[d] - mu2[d]; float a2 = is2[d];
        s1 += d1 * d1 * a1 * a1;
        s2 += d2 * d2 * a2 * a2;
    }
    __half2 g = __floats2half2_rn(expf(-0.5f * s1), expf(-0.5f * s2));
    int2 rec;
    rec.x = sN;
    rec.y = *reinterpret_cast<int*>(&g);
    int pos = offsets[dN] + rk;                    // offsets: 200KB, L2-hot
    __builtin_nontemporal_store(*reinterpret_cast<long long*>(&rec),
                                reinterpret_cast<long long*>(&csr[pos]));
}

// ============================================================================
// agg1 + gemm2: 2 nodes per wave, 32 lanes/row, 8-deep unroll (47.5us floor
// for this access pattern; R5-R7 showed ILP variants don't move it).
// ============================================================================
__global__ __launch_bounds__(256) void agg1_gemm2_kernel(const __half* __restrict__ h,
                                                         const int* __restrict__ offsets,
                                                         const int2* __restrict__ csr,
                                                         const float* __restrict__ b,
                                                         const float* __restrict__ W2,
                                                         __half* __restrict__ h2) {
    __shared__ float xs[8][64];
    const unsigned* h32 = (const unsigned*)h;   // h1 row = 32 dwords
    const int tid = threadIdx.x;
    const int w = tid >> 6, lane = tid & 63;
    const int hf = lane >> 5, p = lane & 31;
    const int ln = w * 2 + hf;                  // local node 0..7
    const int n = blockIdx.x * 8 + ln;
    int beg = offsets[n], end = offsets[n + 1];

    float ax = 0.f, ay = 0.f;
    for (int j = beg; j < end; j += 8) {        // entered only when beg < end
        int j0 = j + 0, j1 = j + 1, j2 = j + 2, j3 = j + 3;
        int j4 = j + 4, j5 = j + 5, j6 = j + 6, j7 = j + 7;
        int e1 = end - 1;
        int2 r0 = csr[(j0 < end) ? j0 : e1];
        int2 r1 = csr[(j1 < end) ? j1 : e1];
        int2 r2 = csr[(j2 < end) ? j2 : e1];
        int2 r3 = csr[(j3 < end) ? j3 : e1];
        int2 r4 = csr[(j4 < end) ? j4 : e1];
        int2 r5 = csr[(j5 < end) ? j5 : e1];
        int2 r6 = csr[(j6 < end) ? j6 : e1];
        int2 r7 = csr[(j7 < end) ? j7 : e1];
        unsigned v0 = h32[(size_t)r0.x * 32 + p];
        unsigned v1 = h32[(size_t)r1.x * 32 + p];
        unsigned v2 = h32[(size_t)r2.x * 32 + p];
        unsigned v3 = h32[(size_t)r3.x * 32 + p];
        unsigned v4 = h32[(size_t)r4.x * 32 + p];
        unsigned v5 = h32[(size_t)r5.x * 32 + p];
        unsigned v6 = h32[(size_t)r6.x * 32 + p];
        unsigned v7 = h32[(size_t)r7.x * 32 + p];
        float g0 = (j0 < end) ? __low2float(*reinterpret_cast<__half2*>(&r0.y)) : 0.f;
        float g1 = (j1 < end) ? __low2float(*reinterpret_cast<__half2*>(&r1.y)) : 0.f;
        float g2 = (j2 < end) ? __low2float(*reinterpret_cast<__half2*>(&r2.y)) : 0.f;
        float g3 = (j3 < end) ? __low2float(*reinterpret_cast<__half2*>(&r3.y)) : 0.f;
        float g4 = (j4 < end) ? __low2float(*reinterpret_cast<__half2*>(&r4.y)) : 0.f;
        float g5 = (j5 < end) ? __low2float(*reinterpret_cast<__half2*>(&r5.y)) : 0.f;
        float g6 = (j6 < end) ? __low2float(*reinterpret_cast<__half2*>(&r6.y)) : 0.f;
        float g7 = (j7 < end) ? __low2float(*reinterpret_cast<__half2*>(&r7.y)) : 0.f;
        float2 f0 = __half22float2(*reinterpret_cast<__half2*>(&v0));
        float2 f1 = __half22float2(*reinterpret_cast<__half2*>(&v1));
        float2 f2 = __half22float2(*reinterpret_cast<__half2*>(&v2));
        float2 f3 = __half22float2(*reinterpret_cast<__half2*>(&v3));
        float2 f4 = __half22float2(*reinterpret_cast<__half2*>(&v4));
        float2 f5 = __half22float2(*reinterpret_cast<__half2*>(&v5));
        float2 f6 = __half22float2(*reinterpret_cast<__half2*>(&v6));
        float2 f7 = __half22float2(*reinterpret_cast<__half2*>(&v7));
        ax += f0.x * g0; ay += f0.y * g0;
        ax += f1.x * g1; ay += f1.y * g1;
        ax += f2.x * g2; ay += f2.y * g2;
        ax += f3.x * g3; ay += f3.y * g3;
        ax += f4.x * g4; ay += f4.y * g4;
        ax += f5.x * g5; ay += f5.y * g5;
        ax += f6.x * g6; ay += f6.y * g6;
        ax += f7.x * g7; ay += f7.y * g7;
    }
    float2 bb = *(const float2*)&b[2 * p];
    *(float2*)&xs[ln][2 * p] = make_float2(ax + bb.x, ay + bb.y);
    __syncthreads();

    // gemm2: 8 nodes x 40 outs = 320 outputs over 256 threads
    for (int o = tid; o < 8 * OUT_FEATS; o += 256) {
        int node = o / OUT_FEATS, t = o % OUT_FEATS;
        const float* xr = xs[node];
        float acc = 0.f;
#pragma unroll
        for (int k = 0; k < N_HIDDEN; ++k)
            acc += xr[k] * W2[k * OUT_FEATS + t];
        h2[(size_t)(blockIdx.x * 8 + node) * OUT_FEATS + t] = __float2half(acc);
    }
}

// ---------------- agg layer 2 + b2 + log_softmax: 8-deep unroll ----------------
__global__ __launch_bounds__(256) void agg2_kernel(const __half* __restrict__ h,
                                                   const int* __restrict__ offsets,
                                                   const int2* __restrict__ csr,
                                                   const float* __restrict__ b,
                                                   float* __restrict__ out) {
    const unsigned* h32 = (const unsigned*)h;   // h2 row = 20 dwords
    const int tid = threadIdx.x;
    const int w = tid >> 6, lane = tid & 63;
    const int hf = lane >> 5, p = lane & 31;
    const int n = blockIdx.x * 8 + w * 2 + hf;
    const int pc = (p < 20) ? p : 19;           // clamp: no divergence, no OOB
    int beg = offsets[n], end = offsets[n + 1];

    float ax = 0.f, ay = 0.f;
    for (int j = beg; j < end; j += 8) {        // entered only when beg < end
        int j0 = j + 0, j1 = j + 1, j2 = j + 2, j3 = j + 3;
        int j4 = j + 4, j5 = j + 5, j6 = j + 6, j7 = j + 7;
        int e1 = end - 1;
        int2 r0 = csr[(j0 < end) ? j0 : e1];
        int2 r1 = csr[(j1 < end) ? j1 : e1];
        int2 r2 = csr[(j2 < end) ? j2 : e1];
        int2 r3 = csr[(j3 < end) ? j3 : e1];
        int2 r4 = csr[(j4 < end) ? j4 : e1];
        int2 r5 = csr[(j5 < end) ? j5 : e1];
        int2 r6 = csr[(j6 < end) ? j6 : e1];
        int2 r7 = csr[(j7 < end) ? j7 : e1];
        unsigned v0 = h32[(size_t)r0.x * 20 + pc];
        unsigned v1 = h32[(size_t)r1.x * 20 + pc];
        unsigned v2 = h32[(size_t)r2.x * 20 + pc];
        unsigned v3 = h32[(size_t)r3.x * 20 + pc];
        unsigned v4 = h32[(size_t)r4.x * 20 + pc];
        unsigned v5 = h32[(size_t)r5.x * 20 + pc];
        unsigned v6 = h32[(size_t)r6.x * 20 + pc];
        unsigned v7 = h32[(size_t)r7.x * 20 + pc];
        float g0 = (j0 < end) ? __high2float(*reinterpret_cast<__half2*>(&r0.y)) : 0.f;
        float g1 = (j1 < end) ? __high2float(*reinterpret_cast<__half2*>(&r1.y)) : 0.f;
        float g2 = (j2 < end) ? __high2float(*reinterpret_cast<__half2*>(&r2.y)) : 0.f;
        float g3 = (j3 < end) ? __high2float(*reinterpret_cast<__half2*>(&r3.y)) : 0.f;
        float g4 = (j4 < end) ? __high2float(*reinterpret_cast<__half2*>(&r4.y)) : 0.f;
        float g5 = (j5 < end) ? __high2float(*reinterpret_cast<__half2*>(&r5.y)) : 0.f;
        float g6 = (j6 < end) ? __high2float(*reinterpret_cast<__half2*>(&r6.y)) : 0.f;
        float g7 = (j7 < end) ? __high2float(*reinterpret_cast<__half2*>(&r7.y)) : 0.f;
        float2 f0 = __half22float2(*reinterpret_cast<__half2*>(&v0));
        float2 f1 = __half22float2(*reinterpret_cast<__half2*>(&v1));
        float2 f2 = __half22float2(*reinterpret_cast<__half2*>(&v2));
        float2 f3 = __half22float2(*reinterpret_cast<__half2*>(&v3));
        float2 f4 = __half22float2(*reinterpret_cast<__half2*>(&v4));
        float2 f5 = __half22float2(*reinterpret_cast<__half2*>(&v5));
        float2 f6 = __half22float2(*reinterpret_cast<__half2*>(&v6));
        float2 f7 = __half22float2(*reinterpret_cast<__half2*>(&v7));
        ax += f0.x * g0; ay += f0.y * g0;
        ax += f1.x * g1; ay += f1.y * g1;
        ax += f2.x * g2; ay += f2.y * g2;
        ax += f3.x * g3; ay += f3.y * g3;
        ax += f4.x * g4; ay += f4.y * g4;
        ax += f5.x * g5; ay += f5.y * g5;
        ax += f6.x * g6; ay += f6.y * g6;
        ax += f7.x * g7; ay += f7.y * g7;
    }

    bool valid = (p < 20);
    float vx = valid ? ax + b[2 * p]     : -INFINITY;
    float vy = valid ? ay + b[2 * p + 1] : -INFINITY;
    float m = fmaxf(vx, vy);
#pragma unroll
    for (int off = 16; off; off >>= 1)
        m = fmaxf(m, __shfl_xor(m, off, 32));   // reduce within each 32-lane half
    float ex = valid ? (expf(vx - m) + expf(vy - m)) : 0.f;
#pragma unroll
    for (int off = 16; off; off >>= 1)
        ex += __shfl_xor(ex, off, 32);
    float ls = logf(ex);
    if (valid) {
        float2 o = make_float2(vx - m - ls, vy - m - ls);
        *(float2*)&out[(size_t)n * OUT_FEATS + 2 * p] = o;
    }
}

extern "C" void kernel_launch(void* const* d_in, const int* in_sizes, int n_in,
                              void* d_out, int out_size, void* d_ws, size_t ws_size,
                              hipStream_t stream) {
    const float* features    = (const float*)d_in[0];
    const float* edge_weight = (const float*)d_in[1];
    const int*   src         = (const int*)d_in[2];
    const int*   dst         = (const int*)d_in[3];
    const float* W1          = (const float*)d_in[4];
    const float* b1          = (const float*)d_in[5];
    const float* mu1         = (const float*)d_in[6];
    const float* is1         = (const float*)d_in[7];
    const float* W2          = (const float*)d_in[8];
    const float* b2          = (const float*)d_in[9];
    const float* mu2         = (const float*)d_in[10];
    const float* is2         = (const float*)d_in[11];
    float* out = (float*)d_out;

    // Workspace: csr int2[800k] 6.4M | h1 half[3.2M] 6.4M | h2 half[2M] 4M
    //            | counts[50k*4 padded] 800K | rank u16[800k] 1.6M
    //            | offsets[50k+1] 200K | partials[256] 1K             (~19.4 MB)
    int2*           csr     = (int2*)d_ws;
    __half*         h1      = (__half*)(csr + N_EDGES);
    __half*         h2      = h1 + (size_t)N_NODES * N_HIDDEN;
    int*            counts  = (int*)(h2 + (size_t)N_NODES * OUT_FEATS);
    unsigned short* rank    = (unsigned short*)(counts + N_NODES * CNT_STRIDE);
    int*            offsets = (int*)(rank + N_EDGES);
    int*            partials= offsets + N_NODES + 1;

    hipMemsetAsync(counts, 0, (size_t)N_NODES * CNT_STRIDE * sizeof(int), stream);

    histgemm_kernel<<<HIST_NB + GT_TILES, 256, 0, stream>>>(
        features, W1, dst, counts, rank, h1);

    scan_partial_kernel<<<SCAN_NB, 256, 0, stream>>>(counts, offsets, partials);
    scan_base_kernel<<<1, 256, 0, stream>>>(partials);
    scan_add_kernel<<<SCAN_NB, 256, 0, stream>>>(offsets, partials);

    fill_kernel<<<FILL_BLOCKS, 256, 0, stream>>>(
        src, dst, edge_weight, mu1, is1, mu2, is2, offsets, rank, csr);

    agg1_gemm2_kernel<<<N_NODES / 8, 256, 0, stream>>>(h1, offsets, csr, b1, W2, h2);

    agg2_kernel<<<N_NODES / 8, 256, 0, stream>>>(h2, offsets, csr, b2, out);
}